// Round 6
// baseline (553.755 us; speedup 1.0000x reference)
//
#include <hip/hip_runtime.h>

#define NB 2
#define NN 512
#define NC 256
#define OUTP 14
#define SS 28
#define CH_SPLIT 4
#define CH_PER_BLK (NC / CH_SPLIT)                     // 64
#define ELEMS_PER_BLK (CH_PER_BLK * OUTP * OUTP)       // 12544
#define POOL_PER_BOX (NC * OUTP * OUTP)                // 50176
#define POOL_TOTAL (NB * NN * POOL_PER_BOX)
#define BOX_OFF POOL_TOTAL
#define KEEP_OFF (POOL_TOTAL + NB * NN * 4)

// K2 patch bound (corrected R5 derivation): sqrt(uv)=s/stride < 28 at EVERY level
// (lvl1: s<112,stride4; lvl2: s<224,stride8; lvl3: s<448,stride16; lvl4: s<=512,stride32)
// => uv < 784; u <= 128 (lvl1). cells <= (0.9643u+3)(0.9643v+3) <= 1126 @ (u=128,v=6.125).
// 128-thread staging: I = ceil(cells/128) <= 9; clamped-tail writes < 9*128 = 1152 = PATCH_MAX.
// LDS/block = 2*1152*4 + 448 tables ~ 9.7 KB -> 16 blocks/CU; 16*2 waves = 32 = 100% occupancy;
// whole 4096-block grid co-resident (4096*128 = 256 CU * 2048 threads).
#define PATCH_MAX 1152

typedef const __attribute__((address_space(1))) unsigned int GU32;
typedef __attribute__((address_space(3))) unsigned int LU32;

// ---------------- K1: fused NMS (sort + suppression matrix + greedy), one block per batch ----
__global__ __launch_bounds__(512) void k_nms(const float* __restrict__ boxes,
                                             const float* __restrict__ scores,
                                             float* __restrict__ dout) {
    int b = blockIdx.x;
    int tid = threadIdx.x;
    __shared__ float sS[NN];
    __shared__ int sI[NN];
    __shared__ float4 sB[NN];
    __shared__ float sA[NN];
    __shared__ int sL[NN];
    __shared__ unsigned long long sup[NN][8];   // 32 KB
    __shared__ unsigned long long skw[8];
    __shared__ int korig[NN];

    sS[tid] = scores[b * NN + tid];
    sI[tid] = tid;
    __syncthreads();
    for (int k = 2; k <= NN; k <<= 1) {
        for (int j = k >> 1; j > 0; j >>= 1) {
            int ixj = tid ^ j;
            if (ixj > tid) {
                float s1 = sS[tid], s2 = sS[ixj];
                int i1 = sI[tid], i2 = sI[ixj];
                bool lt = (s1 > s2) || (s1 == s2 && i1 < i2);
                bool up = ((tid & k) == 0);
                if (up ? !lt : lt) {
                    sS[tid] = s2; sS[ixj] = s1;
                    sI[tid] = i2; sI[ixj] = i1;
                }
            }
            __syncthreads();
        }
    }
    {
        int o = sI[tid];
        float4 bx = ((const float4*)boxes)[b * NN + o];
        float w = bx.z, h = bx.w;
        float x1 = bx.x - w * 0.5f, y1 = bx.y - h * 0.5f;
        float x2 = bx.x + w * 0.5f, y2 = bx.y + h * 0.5f;
        float s = sqrtf(w * h);
        int lvl = (s < 112.f) ? 1 : ((s < 224.f) ? 2 : ((s < 448.f) ? 3 : 4));
        sB[tid] = make_float4(x1, y1, x2, y2);
        sA[tid] = (x2 - x1) * (y2 - y1);
        sL[tid] = lvl;
    }
    __syncthreads();
    {
        float4 bi = sB[tid];
        float areai = sA[tid];
        int il = sL[tid];
        for (int cg = 0; cg < 8; ++cg) {
            unsigned long long m = 0ull;
            int jb = cg << 6;
#pragma unroll 4
            for (int k = 0; k < 64; ++k) {
                int j = jb + k;
                float4 bj = sB[j];
                float xx1 = fmaxf(bi.x, bj.x);
                float yy1 = fmaxf(bi.y, bj.y);
                float xx2 = fminf(bi.z, bj.z);
                float yy2 = fminf(bi.w, bj.w);
                float inter = fmaxf(xx2 - xx1, 0.0f) * fmaxf(yy2 - yy1, 0.0f);
                float denom = areai + sA[j] - inter + 1e-9f;
                bool sp = (j > tid) && (sL[j] == il) && ((inter / denom) > 0.5f);
                m |= sp ? (1ull << k) : 0ull;
            }
            sup[tid][cg] = m;
        }
    }
    __syncthreads();
    if (tid < 64) {
        int myw = tid & 7;
        unsigned long long kwl = ~0ull;
        for (int w = 0; w < 8; ++w) {
            unsigned long long aw = __shfl(kwl, w);
            int ibase = w << 6;
            for (int bb = 0; bb < 64; ++bb) {
                int i = ibase + bb;
                unsigned long long rw = sup[i][w];
                unsigned long long rl = sup[i][myw];
                if ((aw >> bb) & 1ull) {
                    aw &= ~rw;
                    kwl &= ~rl;
                }
            }
        }
        if (tid < 8) skw[tid] = kwl;
    }
    __syncthreads();
    korig[sI[tid]] = (int)((skw[tid >> 6] >> (tid & 63)) & 1ull);
    __syncthreads();
    {
        float4 bx = ((const float4*)boxes)[b * NN + tid];
        float kf = korig[tid] ? 1.0f : 0.0f;
        float x1 = (bx.x - bx.z * 0.5f) * kf;
        float y1 = (bx.y - bx.w * 0.5f) * kf;
        float x2 = (bx.x + bx.z * 0.5f) * kf;
        float y2 = (bx.y + bx.w * 0.5f) * kf;
        ((float4*)(dout + BOX_OFF))[b * NN + tid] = make_float4(x1, y1, x2, y2);
        dout[KEEP_OFF + b * NN + tid] = kf;
    }
}

// ---------------- K2: ROI align, 128-thr block-coop channel pipeline, 100% occupancy ---------
// Per (box, 64-ch chunk) block: 64 channels staged one-at-a-time into a double-buffered
// LDS patch via global_load_lds; counted vmcnt keeps next channel's loads in flight across
// raw barriers. Uniform load count (clamped tail) => per-wave vmcnt arithmetic exact.
__global__ __launch_bounds__(128, 8) void k_roi(const float* __restrict__ p4,
                                                const float* __restrict__ p8,
                                                const float* __restrict__ p16,
                                                const float* __restrict__ p32,
                                                const float* __restrict__ boxes,
                                                float* __restrict__ dout) {
    int blk = blockIdx.x;
    int box = blk >> 2;
    int chunk = blk & 3;
    int b = box >> 9;
    int tid = threadIdx.x;
    float* obase = dout + (size_t)box * POOL_PER_BOX + (size_t)chunk * ELEMS_PER_BLK;
    float keepf = dout[KEEP_OFF + box];
    if (keepf < 0.5f) {
        float4 z = make_float4(0.f, 0.f, 0.f, 0.f);
        float4* o4 = (float4*)obase;
        for (int i = tid; i < ELEMS_PER_BLK / 4; i += 128) o4[i] = z;
        return;
    }
    float4 bx = ((const float4*)boxes)[box];
    float w = bx.z, h = bx.w;
    float s = sqrtf(w * h);
    int lvl = (s < 112.f) ? 0 : ((s < 224.f) ? 1 : ((s < 448.f) ? 2 : 3));
    const float* feat = (lvl == 0) ? p4 : ((lvl == 1) ? p8 : ((lvl == 2) ? p16 : p32));
    int HW = 256 >> lvl;
    float inv = 1.0f / (float)(4 << lvl);
    int planesz = HW * HW;
    const float* plane0 = feat + (size_t)b * NC * planesz + (size_t)(chunk * CH_PER_BLK) * planesz;

    // uniform patch bounds; x0/y0 clamped to HW-2 so corner c0+1/r0+1 always valid (lx->1.0 exact)
    float x1r = (bx.x - w * 0.5f) * inv;
    float bwr = w * inv / 14.0f;
    float y1r = (bx.y - h * 0.5f) * inv;
    float bhr = h * inv / 14.0f;
    float hwm1 = (float)(HW - 1);
    float xs_first = fminf(fmaxf(x1r + 0.25f * bwr, 0.0f), hwm1);
    float xs_last  = fminf(fmaxf(x1r + 13.75f * bwr, 0.0f), hwm1);
    float ys_first = fminf(fmaxf(y1r + 0.25f * bhr, 0.0f), hwm1);
    float ys_last  = fminf(fmaxf(y1r + 13.75f * bhr, 0.0f), hwm1);
    int x_lo = min((int)floorf(xs_first), HW - 2);
    int x_hi = min((int)floorf(xs_last) + 1, HW - 1);
    int y_lo = min((int)floorf(ys_first), HW - 2);
    int y_hi = min((int)floorf(ys_last) + 1, HW - 1);
    int PW = x_hi - x_lo + 1;           // >= 2
    int PH = y_hi - y_lo + 1;           // >= 2
    int cells = PW * PH;                // <= ~1126 (header derivation)
    int cm1 = cells - 1;
    float invPW = 1.0f / (float)PW;
    int I = (cells + 127) >> 7;         // 1..9, block-uniform

    __shared__ float patch[2][PATCH_MAX];         // 9216 B -> 16 blocks/CU
    __shared__ int sXc0[SS], sYoff[SS];
    __shared__ float sLX[SS], sLY[SS];

    if (tid < SS) {
        float g = (tid + 0.5f) * 0.5f;
        float xs = fminf(fmaxf(x1r + g * bwr, 0.0f), hwm1);
        int x0 = min((int)floorf(xs), HW - 2);
        sXc0[tid] = x0 - x_lo;
        sLX[tid] = xs - (float)x0;
        float ys = fminf(fmaxf(y1r + g * bhr, 0.0f), hwm1);
        int y0 = min((int)floorf(ys), HW - 2);
        sYoff[tid] = (y0 - y_lo) * PW;            // premultiplied row offset
        sLY[tid] = ys - (float)y0;
    }
    // (first in-loop barrier covers the table writes)

    const int base_gidx = y_lo * HW + x_lo;
    const float* wplane = plane0 + base_gidx;
    const int hwmpw = HW - PW;

    // One channel staged by the whole 128-thread block: exactly I global_load_lds per thread
    // (dest = wave-uniform base + lane*4; tail lanes clamp the GLOBAL index only; max LDS
    // index I*128-1 <= 1151 < PATCH_MAX).
#define STAGE(j, bufi)                                                                      \
    do {                                                                                    \
        const float* pl_ = wplane + (size_t)(j) * planesz;                                  \
        LU32* dst_ = (LU32*)&patch[bufi][0];                                                \
        for (int k_ = 0; k_ < I; ++k_) {                                                    \
            int i_ = tid + (k_ << 7);                                                       \
            int iq_ = min(i_, cm1);                                                         \
            int row_ = (int)(((float)iq_ + 0.5f) * invPW);                                  \
            int voff_ = row_ * hwmpw + iq_; /* row*HW + col */                              \
            __builtin_amdgcn_global_load_lds((GU32*)(pl_ + voff_), dst_ + i_, 4, 0, 0);     \
        }                                                                                   \
    } while (0)

#define VMCNT(N) asm volatile("s_waitcnt vmcnt(" #N ")" ::: "memory")

    STAGE(0, 0);

    for (int j = 0; j < CH_PER_BLK; ++j) {
        if (j + 1 < CH_PER_BLK) {
            STAGE(j + 1, (j + 1) & 1);
            // drain channel j's loads (and older stores); leave j+1's I loads in flight
            switch (I) {
                case 1:  VMCNT(1);  break;
                case 2:  VMCNT(2);  break;
                case 3:  VMCNT(3);  break;
                case 4:  VMCNT(4);  break;
                case 5:  VMCNT(5);  break;
                case 6:  VMCNT(6);  break;
                case 7:  VMCNT(7);  break;
                case 8:  VMCNT(8);  break;
                default: VMCNT(9);  break;
            }
        } else {
            VMCNT(0);
        }
        __builtin_amdgcn_s_barrier();      // channel j fully staged (all waves)
        asm volatile("" ::: "memory");

        const float* P = &patch[j & 1][0];
        float* oc = obase + j * 196;
        if (tid < 98) {                    // one output PAIR per thread (98 pairs = 196 outs)
            int p0 = tid << 1;
            int py = p0 / 14;
            int px = p0 - py * 14;         // even
            int iy = py << 1;
            int ro0 = sYoff[iy],  ro1 = sYoff[iy + 1];
            float ly0 = sLY[iy],  ly1 = sLY[iy + 1];
            float2 r;
#pragma unroll
            for (int q = 0; q < 2; ++q) {
                int ix = (px + q) << 1;
                int c00 = sXc0[ix],   c01 = sXc0[ix + 1];
                float lx0 = sLX[ix],  lx1 = sLX[ix + 1];
                float acc = 0.f;
#define SAMPLE(RO, LY, CC, LX)                                        \
                {                                                     \
                    const float* q_ = P + (RO) + (CC);                \
                    float f00 = q_[0], f01 = q_[1];                   \
                    const float* q2_ = q_ + PW;                       \
                    float f10 = q2_[0], f11 = q2_[1];                 \
                    float top = f00 + (LX) * (f01 - f00);             \
                    float bot = f10 + (LX) * (f11 - f10);             \
                    acc += top + (LY) * (bot - top);                  \
                }
                SAMPLE(ro0, ly0, c00, lx0)
                SAMPLE(ro0, ly0, c01, lx1)
                SAMPLE(ro1, ly1, c00, lx0)
                SAMPLE(ro1, ly1, c01, lx1)
#undef SAMPLE
                if (q == 0) r.x = acc * 0.25f; else r.y = acc * 0.25f;
            }
            *(float2*)(oc + p0) = r;
        }

        if (j + 1 < CH_PER_BLK) {
            asm volatile("" ::: "memory");
            __builtin_amdgcn_s_barrier();  // all waves done reading buf before restage
            asm volatile("" ::: "memory");
        }
    }
#undef STAGE
#undef VMCNT
}

extern "C" void kernel_launch(void* const* d_in, const int* in_sizes, int n_in,
                              void* d_out, int out_size, void* d_ws, size_t ws_size,
                              hipStream_t stream) {
    const float* p4 = (const float*)d_in[0];
    const float* p8 = (const float*)d_in[1];
    const float* p16 = (const float*)d_in[2];
    const float* p32 = (const float*)d_in[3];
    const float* boxes = (const float*)d_in[4];
    const float* scores = (const float*)d_in[5];
    float* out = (float*)d_out;

    k_nms<<<NB, NN, 0, stream>>>(boxes, scores, out);
    k_roi<<<NB * NN * CH_SPLIT, 128, 0, stream>>>(p4, p8, p16, p32, boxes, out);
}

// Round 9
// 541.910 us; speedup vs baseline: 1.0219x; 1.0219x over previous
//
#include <hip/hip_runtime.h>

#define NB 2
#define NN 512
#define NC 256
#define OUTP 14
#define SS 28
#define CH_SPLIT 4
#define CH_PER_BLK (NC / CH_SPLIT)                     // 64
#define ELEMS_PER_BLK (CH_PER_BLK * OUTP * OUTP)       // 12544
#define POOL_PER_BOX (NC * OUTP * OUTP)                // 50176
#define POOL_TOTAL (NB * NN * POOL_PER_BOX)
#define BOX_OFF POOL_TOTAL
#define KEEP_OFF (POOL_TOTAL + NB * NN * 4)

// K2 patch bound: sqrt(uv)=s/stride < 28 at EVERY level => uv < 784; u <= 128 (lvl1).
// cells <= (0.9643u+3)(0.9643v+3) <= 1126 @ (u=128,v=6.125).
// I = ceil(cells/128) <= 9; clamped-tail writes < 9*128 = 1152 = PATCH_MAX.
// LDS/block ~ 9.7 KB. Issue-diet round: channel-invariant tables/offsets hoisted to
// registers; pipeline templated on I (compile-time vmcnt, voff in registers).
#define PATCH_MAX 1152

typedef const __attribute__((address_space(1))) unsigned int GU32;
typedef __attribute__((address_space(3))) unsigned int LU32;

template <int N> struct IC { static constexpr int value = N; };

template <int IT> __device__ __forceinline__ void vm_leave() {
    if constexpr (IT == 1)      asm volatile("s_waitcnt vmcnt(1)" ::: "memory");
    else if constexpr (IT == 2) asm volatile("s_waitcnt vmcnt(2)" ::: "memory");
    else if constexpr (IT == 3) asm volatile("s_waitcnt vmcnt(3)" ::: "memory");
    else if constexpr (IT == 4) asm volatile("s_waitcnt vmcnt(4)" ::: "memory");
    else if constexpr (IT == 5) asm volatile("s_waitcnt vmcnt(5)" ::: "memory");
    else if constexpr (IT == 6) asm volatile("s_waitcnt vmcnt(6)" ::: "memory");
    else if constexpr (IT == 7) asm volatile("s_waitcnt vmcnt(7)" ::: "memory");
    else if constexpr (IT == 8) asm volatile("s_waitcnt vmcnt(8)" ::: "memory");
    else                        asm volatile("s_waitcnt vmcnt(9)" ::: "memory");
}

// ---------------- K1: fused NMS (sort + suppression matrix + greedy), one block per batch ----
__global__ __launch_bounds__(512) void k_nms(const float* __restrict__ boxes,
                                             const float* __restrict__ scores,
                                             float* __restrict__ dout) {
    int b = blockIdx.x;
    int tid = threadIdx.x;
    __shared__ float sS[NN];
    __shared__ int sI[NN];
    __shared__ float4 sB[NN];
    __shared__ float sA[NN];
    __shared__ int sL[NN];
    __shared__ unsigned long long sup[NN][8];   // 32 KB
    __shared__ unsigned long long skw[8];
    __shared__ int korig[NN];

    sS[tid] = scores[b * NN + tid];
    sI[tid] = tid;
    __syncthreads();
    for (int k = 2; k <= NN; k <<= 1) {
        for (int j = k >> 1; j > 0; j >>= 1) {
            int ixj = tid ^ j;
            if (ixj > tid) {
                float s1 = sS[tid], s2 = sS[ixj];
                int i1 = sI[tid], i2 = sI[ixj];
                bool lt = (s1 > s2) || (s1 == s2 && i1 < i2);
                bool up = ((tid & k) == 0);
                if (up ? !lt : lt) {
                    sS[tid] = s2; sS[ixj] = s1;
                    sI[tid] = i2; sI[ixj] = i1;
                }
            }
            __syncthreads();
        }
    }
    {
        int o = sI[tid];
        float4 bx = ((const float4*)boxes)[b * NN + o];
        float w = bx.z, h = bx.w;
        float x1 = bx.x - w * 0.5f, y1 = bx.y - h * 0.5f;
        float x2 = bx.x + w * 0.5f, y2 = bx.y + h * 0.5f;
        float s = sqrtf(w * h);
        int lvl = (s < 112.f) ? 1 : ((s < 224.f) ? 2 : ((s < 448.f) ? 3 : 4));
        sB[tid] = make_float4(x1, y1, x2, y2);
        sA[tid] = (x2 - x1) * (y2 - y1);
        sL[tid] = lvl;
    }
    __syncthreads();
    {
        float4 bi = sB[tid];
        float areai = sA[tid];
        int il = sL[tid];
        for (int cg = 0; cg < 8; ++cg) {
            unsigned long long m = 0ull;
            int jb = cg << 6;
#pragma unroll 4
            for (int k = 0; k < 64; ++k) {
                int j = jb + k;
                float4 bj = sB[j];
                float xx1 = fmaxf(bi.x, bj.x);
                float yy1 = fmaxf(bi.y, bj.y);
                float xx2 = fminf(bi.z, bj.z);
                float yy2 = fminf(bi.w, bj.w);
                float inter = fmaxf(xx2 - xx1, 0.0f) * fmaxf(yy2 - yy1, 0.0f);
                float denom = areai + sA[j] - inter + 1e-9f;
                bool sp = (j > tid) && (sL[j] == il) && ((inter / denom) > 0.5f);
                m |= sp ? (1ull << k) : 0ull;
            }
            sup[tid][cg] = m;
        }
    }
    __syncthreads();
    if (tid < 64) {
        int myw = tid & 7;
        unsigned long long kwl = ~0ull;
        for (int w = 0; w < 8; ++w) {
            unsigned long long aw = __shfl(kwl, w);
            int ibase = w << 6;
            for (int bb = 0; bb < 64; ++bb) {
                int i = ibase + bb;
                unsigned long long rw = sup[i][w];
                unsigned long long rl = sup[i][myw];
                if ((aw >> bb) & 1ull) {
                    aw &= ~rw;
                    kwl &= ~rl;
                }
            }
        }
        if (tid < 8) skw[tid] = kwl;
    }
    __syncthreads();
    korig[sI[tid]] = (int)((skw[tid >> 6] >> (tid & 63)) & 1ull);
    __syncthreads();
    {
        float4 bx = ((const float4*)boxes)[b * NN + tid];
        float kf = korig[tid] ? 1.0f : 0.0f;
        float x1 = (bx.x - bx.z * 0.5f) * kf;
        float y1 = (bx.y - bx.w * 0.5f) * kf;
        float x2 = (bx.x + bx.z * 0.5f) * kf;
        float y2 = (bx.y + bx.w * 0.5f) * kf;
        ((float4*)(dout + BOX_OFF))[b * NN + tid] = make_float4(x1, y1, x2, y2);
        dout[KEEP_OFF + b * NN + tid] = kf;
    }
}

// ---------------- K2: ROI align, instruction-diet channel pipeline ----------------
__global__ __launch_bounds__(128, 6) void k_roi(const float* __restrict__ p4,
                                                const float* __restrict__ p8,
                                                const float* __restrict__ p16,
                                                const float* __restrict__ p32,
                                                const float* __restrict__ boxes,
                                                float* __restrict__ dout) {
    int blk = blockIdx.x;
    int box = blk >> 2;
    int chunk = blk & 3;
    int b = box >> 9;
    int tid = threadIdx.x;
    float* obase = dout + (size_t)box * POOL_PER_BOX + (size_t)chunk * ELEMS_PER_BLK;
    float keepf = dout[KEEP_OFF + box];
    if (keepf < 0.5f) {
        float4 z = make_float4(0.f, 0.f, 0.f, 0.f);
        float4* o4 = (float4*)obase;
        for (int i = tid; i < ELEMS_PER_BLK / 4; i += 128) o4[i] = z;
        return;
    }
    float4 bx = ((const float4*)boxes)[box];
    float w = bx.z, h = bx.w;
    float s = sqrtf(w * h);
    int lvl = (s < 112.f) ? 0 : ((s < 224.f) ? 1 : ((s < 448.f) ? 2 : 3));
    const float* feat = (lvl == 0) ? p4 : ((lvl == 1) ? p8 : ((lvl == 2) ? p16 : p32));
    int HW = 256 >> lvl;
    float inv = 1.0f / (float)(4 << lvl);
    int planesz = HW * HW;
    const float* plane0 = feat + (size_t)b * NC * planesz + (size_t)(chunk * CH_PER_BLK) * planesz;

    // uniform patch bounds; x0/y0 clamped to HW-2 so corner c0+1/r0+1 always valid (lx->1.0 exact)
    float x1r = (bx.x - w * 0.5f) * inv;
    float bwr = w * inv / 14.0f;
    float y1r = (bx.y - h * 0.5f) * inv;
    float bhr = h * inv / 14.0f;
    float hwm1 = (float)(HW - 1);
    float xs_first = fminf(fmaxf(x1r + 0.25f * bwr, 0.0f), hwm1);
    float xs_last  = fminf(fmaxf(x1r + 13.75f * bwr, 0.0f), hwm1);
    float ys_first = fminf(fmaxf(y1r + 0.25f * bhr, 0.0f), hwm1);
    float ys_last  = fminf(fmaxf(y1r + 13.75f * bhr, 0.0f), hwm1);
    int x_lo = min((int)floorf(xs_first), HW - 2);
    int x_hi = min((int)floorf(xs_last) + 1, HW - 1);
    int y_lo = min((int)floorf(ys_first), HW - 2);
    int y_hi = min((int)floorf(ys_last) + 1, HW - 1);
    int PW = x_hi - x_lo + 1;           // >= 2
    int PH = y_hi - y_lo + 1;           // >= 2
    int cells = PW * PH;                // <= ~1126
    int cm1 = cells - 1;
    float invPW = 1.0f / (float)PW;
    int I = (cells + 127) >> 7;         // 1..9, block-uniform

    __shared__ float patch[2][PATCH_MAX];         // 9216 B
    __shared__ int sXc0[SS], sYoff[SS];
    __shared__ float sLX[SS], sLY[SS];

    if (tid < SS) {
        float g = (tid + 0.5f) * 0.5f;
        float xs = fminf(fmaxf(x1r + g * bwr, 0.0f), hwm1);
        int x0 = min((int)floorf(xs), HW - 2);
        sXc0[tid] = x0 - x_lo;
        sLX[tid] = xs - (float)x0;
        float ys = fminf(fmaxf(y1r + g * bhr, 0.0f), hwm1);
        int y0 = min((int)floorf(ys), HW - 2);
        sYoff[tid] = (y0 - y_lo) * PW;            // premultiplied row offset
        sLY[tid] = ys - (float)y0;
    }
    __syncthreads();    // tables ready (hoist reads them immediately below)

    // ---- hoist ALL channel-invariant state into registers ----
    int p0 = tid << 1;
    bool act = (tid < 98);              // one output pair per active thread
    float ly0 = 0.f, ly1 = 0.f, lxA = 0.f, lxB = 0.f, lxC = 0.f, lxD = 0.f;
    int oAA = 0, oAAd = 0, oBA = 0, oBAd = 0;     // x=A: top rows (ro0,+PW), bot rows (ro1,+PW)
    int oAB = 0, oABd = 0, oBB = 0, oBBd = 0;     // x=B
    int oAC = 0, oACd = 0, oBC = 0, oBCd = 0;     // x=C
    int oAD = 0, oADd = 0, oBD = 0, oBDd = 0;     // x=D
    if (act) {
        int py = p0 / 14;
        int px = p0 - py * 14;          // even
        int iy = py << 1;
        int ro0 = sYoff[iy], ro1 = sYoff[iy + 1];
        ly0 = sLY[iy]; ly1 = sLY[iy + 1];
        int ix = px << 1;
        int cA = sXc0[ix], cB = sXc0[ix + 1], cC = sXc0[ix + 2], cD = sXc0[ix + 3];
        lxA = sLX[ix]; lxB = sLX[ix + 1]; lxC = sLX[ix + 2]; lxD = sLX[ix + 3];
        oAA = ro0 + cA; oAAd = oAA + PW; oBA = ro1 + cA; oBAd = oBA + PW;
        oAB = ro0 + cB; oABd = oAB + PW; oBB = ro1 + cB; oBBd = oBB + PW;
        oAC = ro0 + cC; oACd = oAC + PW; oBC = ro1 + cC; oBCd = oBC + PW;
        oAD = ro0 + cD; oADd = oAD + PW; oBD = ro1 + cD; oBDd = oBD + PW;
    }

    const int base_gidx = y_lo * HW + x_lo;
    const float* chbase = plane0 + base_gidx;
    const int hwmpw = HW - PW;

    auto pipeline = [&](auto icI) {
        constexpr int IT = decltype(icI)::value;
        // staging offsets: channel-invariant, computed ONCE into registers
        int voff[IT];
#pragma unroll
        for (int k = 0; k < IT; ++k) {
            int i_ = tid + (k << 7);
            int iq_ = min(i_, cm1);
            int row_ = (int)(((float)iq_ + 0.5f) * invPW);
            voff[k] = row_ * hwmpw + iq_;       // row*HW + col
        }
        // Per-channel stage: IT global_load_lds (dest = wave-uniform base + lane*4;
        // tail lanes clamp only the GLOBAL index; max LDS index IT*128-1 <= 1151 < PATCH_MAX)
#define STG(JCH, DSTP)                                                                     \
        {                                                                                  \
            const float* pl_ = chbase + (size_t)(JCH) * planesz;                           \
            _Pragma("unroll")                                                              \
            for (int k_ = 0; k_ < IT; ++k_)                                                \
                __builtin_amdgcn_global_load_lds((GU32*)(pl_ + voff[k_]),                  \
                                                 (DSTP) + (tid + (k_ << 7)), 4, 0, 0);     \
        }
        const float* Pc = &patch[0][0];
        const float* Pn = &patch[1][0];
        LU32* Lc = (LU32*)&patch[0][0];
        LU32* Ln = (LU32*)&patch[1][0];
        STG(0, Lc);
        float* ocur = obase + p0;
        for (int j = 0; j < CH_PER_BLK; ++j) {
            if (j + 1 < CH_PER_BLK) {
                STG(j + 1, Ln);
                vm_leave<IT>();      // drain ch j's loads + older stores; leave ch j+1's IT in flight
            } else {
                asm volatile("s_waitcnt vmcnt(0)" ::: "memory");
            }
            __builtin_amdgcn_s_barrier();        // channel j fully staged (all waves)
            asm volatile("" ::: "memory");

            if (act) {
                const float* P = Pc;
                float ax = 0.f, ay = 0.f;
#define S(ACC, O, OD, LX, LY)                                          \
                {                                                      \
                    float f00 = P[O], f01 = P[(O) + 1];                \
                    float f10 = P[OD], f11 = P[(OD) + 1];              \
                    float top = f00 + (LX) * (f01 - f00);              \
                    float bot = f10 + (LX) * (f11 - f10);              \
                    ACC += top + (LY) * (bot - top);                   \
                }
                S(ax, oAA, oAAd, lxA, ly0)
                S(ax, oAB, oABd, lxB, ly0)
                S(ax, oBA, oBAd, lxA, ly1)
                S(ax, oBB, oBBd, lxB, ly1)
                S(ay, oAC, oACd, lxC, ly0)
                S(ay, oAD, oADd, lxD, ly0)
                S(ay, oBC, oBCd, lxC, ly1)
                S(ay, oBD, oBDd, lxD, ly1)
#undef S
                *(float2*)ocur = make_float2(ax * 0.25f, ay * 0.25f);
            }
            ocur += 196;

            if (j + 1 < CH_PER_BLK) {
                asm volatile("" ::: "memory");
                __builtin_amdgcn_s_barrier();    // all waves done reading buf before restage
                asm volatile("" ::: "memory");
                const float* tp = Pc; Pc = Pn; Pn = tp;
                LU32* tl = Lc; Lc = Ln; Ln = tl;
            }
        }
#undef STG
    };

    switch (I) {
        case 1: pipeline(IC<1>{}); break;
        case 2: pipeline(IC<2>{}); break;
        case 3: pipeline(IC<3>{}); break;
        case 4: pipeline(IC<4>{}); break;
        case 5: pipeline(IC<5>{}); break;
        case 6: pipeline(IC<6>{}); break;
        case 7: pipeline(IC<7>{}); break;
        case 8: pipeline(IC<8>{}); break;
        default: pipeline(IC<9>{}); break;
    }
}

extern "C" void kernel_launch(void* const* d_in, const int* in_sizes, int n_in,
                              void* d_out, int out_size, void* d_ws, size_t ws_size,
                              hipStream_t stream) {
    const float* p4 = (const float*)d_in[0];
    const float* p8 = (const float*)d_in[1];
    const float* p16 = (const float*)d_in[2];
    const float* p32 = (const float*)d_in[3];
    const float* boxes = (const float*)d_in[4];
    const float* scores = (const float*)d_in[5];
    float* out = (float*)d_out;

    k_nms<<<NB, NN, 0, stream>>>(boxes, scores, out);
    k_roi<<<NB * NN * CH_SPLIT, 128, 0, stream>>>(p4, p8, p16, p32, boxes, out);
}